// Round 1
// baseline (641.817 us; speedup 1.0000x reference)
//
#include <hip/hip_runtime.h>

#define NUM_C 512
#define HW    32768     // 128*256
#define K     19
#define NT    256

// ---------------------------------------------------------------------------
// K1: per-(b,c)-plane segment sums over classes, for S and T simultaneously.
// grid = B*C = 1024 blocks; block = 256 threads.
// LDS: acc[k][tid] per-thread slots -> bank = tid%32 (2 lanes/bank = free),
// atomicAdd on LDS lowers to ds_add_f32 (1 LDS op per accumulate).
// ---------------------------------------------------------------------------
__global__ __launch_bounds__(NT) void seg_sum_kernel(
    const float* __restrict__ S, const float* __restrict__ T,
    const int* __restrict__ lbl,
    float* __restrict__ sumsS, float* __restrict__ sumsT)
{
    __shared__ float accS[K * NT];
    __shared__ float accT[K * NT];
    const int tid = threadIdx.x;

#pragma unroll
    for (int k = 0; k < K; ++k) {
        accS[k * NT + tid] = 0.f;
        accT[k * NT + tid] = 0.f;
    }
    __syncthreads();

    const int plane = blockIdx.x;        // b*512 + c
    const int b     = plane >> 9;
    const float4* S4 = (const float4*)(S + (size_t)plane * HW);
    const float4* T4 = (const float4*)(T + (size_t)plane * HW);
    const int4*   L4 = (const int4*)(lbl + (size_t)b * HW);

    for (int i = tid; i < HW / 4; i += NT) {
        float4 s = S4[i];
        float4 t = T4[i];
        int4   l = L4[i];
        atomicAdd(&accS[l.x * NT + tid], s.x);
        atomicAdd(&accT[l.x * NT + tid], t.x);
        atomicAdd(&accS[l.y * NT + tid], s.y);
        atomicAdd(&accT[l.y * NT + tid], t.y);
        atomicAdd(&accS[l.z * NT + tid], s.z);
        atomicAdd(&accT[l.z * NT + tid], t.z);
        atomicAdd(&accS[l.w * NT + tid], s.w);
        atomicAdd(&accT[l.w * NT + tid], t.w);
    }
    __syncthreads();

    // tree-reduce the 256 per-thread slots for each of the 2*K rows
    for (int s = NT / 2; s > 0; s >>= 1) {
        if (tid < s) {
#pragma unroll
            for (int k = 0; k < K; ++k) {
                accS[k * NT + tid] += accS[k * NT + tid + s];
                accT[k * NT + tid] += accT[k * NT + tid + s];
            }
        }
        __syncthreads();
    }
    if (tid < K) {
        sumsS[(size_t)plane * K + tid] = accS[tid * NT];
        sumsT[(size_t)plane * K + tid] = accT[tid * NT];
    }
}

// ---------------------------------------------------------------------------
// K2: single block. counts -> centers -> pairwise dots -> cosine -> MSE loss.
// hist buffer (2*K*NT floats = 38912 B) is reused as the center buffer
// (NUM_C*K = 9728 floats = same size).
// ---------------------------------------------------------------------------
__global__ __launch_bounds__(NT) void finalize_kernel(
    const float* __restrict__ sumsS, const float* __restrict__ sumsT,
    const int* __restrict__ lbl, float* __restrict__ out)
{
    __shared__ float hist[2 * K * NT];   // reused as center[NUM_C*K]
    __shared__ float cnt[2 * K];
    __shared__ float pS[K * K];
    __shared__ float pT[K * K];
    __shared__ float red[NT];
    const int tid = threadIdx.x;

    // --- label histogram (exact integer counts in fp32, per-thread slots) ---
#pragma unroll
    for (int j = 0; j < 2 * K; ++j) hist[j * NT + tid] = 0.f;
    __syncthreads();
    for (int i = tid; i < 2 * HW; i += NT) {
        int b = i >> 15;          // i / HW
        int l = lbl[i];
        hist[(b * K + l) * NT + tid] += 1.0f;   // exclusive slot, no atomic
    }
    __syncthreads();
    for (int s = NT / 2; s > 0; s >>= 1) {
        if (tid < s)
#pragma unroll
            for (int j = 0; j < 2 * K; ++j)
                hist[j * NT + tid] += hist[j * NT + tid + s];
        __syncthreads();
    }
    if (tid < 2 * K) cnt[tid] = hist[tid * NT] + 1e-6f;
    __syncthreads();

    float* center = hist;   // [NUM_C * K], layout center[c*K + k]
    float lossacc = 0.f;

    for (int b = 0; b < 2; ++b) {
        // ---- S centers + dots ----
        for (int i = tid; i < NUM_C * K; i += NT) {
            int c = i / K, k = i - c * K;
            center[i] = sumsS[(size_t)(b * NUM_C + c) * K + k] / cnt[b * K + k];
        }
        __syncthreads();
        for (int p = tid; p < K * K; p += NT) {
            int i = p / K, j = p - (p / K) * K;
            float d = 0.f;
            for (int c = 0; c < NUM_C; ++c)
                d += center[c * K + i] * center[c * K + j];
            pS[p] = d;
        }
        __syncthreads();

        // ---- T centers + dots ----
        for (int i = tid; i < NUM_C * K; i += NT) {
            int c = i / K, k = i - c * K;
            center[i] = sumsT[(size_t)(b * NUM_C + c) * K + k] / cnt[b * K + k];
        }
        __syncthreads();
        for (int p = tid; p < K * K; p += NT) {
            int i = p / K, j = p - (p / K) * K;
            float d = 0.f;
            for (int c = 0; c < NUM_C; ++c)
                d += center[c * K + i] * center[c * K + j];
            pT[p] = d;
        }
        __syncthreads();

        // ---- cosine-normalize via diagonal (dots[k][k] == ||c_k||^2) ----
        for (int p = tid; p < K * K; p += NT) {
            int i = p / K, j = p - (p / K) * K;
            float nsi = fmaxf(sqrtf(pS[i * K + i]), 1e-8f);
            float nsj = fmaxf(sqrtf(pS[j * K + j]), 1e-8f);
            float nti = fmaxf(sqrtf(pT[i * K + i]), 1e-8f);
            float ntj = fmaxf(sqrtf(pT[j * K + j]), 1e-8f);
            float d = pS[p] / (nsi * nsj) - pT[p] / (nti * ntj);
            lossacc += d * d;
        }
        __syncthreads();   // pS/pT/center reused next batch
    }

    red[tid] = lossacc;
    __syncthreads();
    for (int s = NT / 2; s > 0; s >>= 1) {
        if (tid < s) red[tid] += red[tid + s];
        __syncthreads();
    }
    if (tid == 0)
        out[0] = red[0] * (1.0f / (2.0f * K * K));   // mean over [B,K,K], LOSS_WEIGHT=1
}

extern "C" void kernel_launch(void* const* d_in, const int* in_sizes, int n_in,
                              void* d_out, int out_size, void* d_ws, size_t ws_size,
                              hipStream_t stream) {
    const float* S   = (const float*)d_in[0];   // preds_S  [2,512,128,256] fp32
    const float* T   = (const float*)d_in[1];   // preds_T  [2,512,128,256] fp32
    const int*   lbl = (const int*)d_in[2];     // target   [2,1,128,256] int32
    float* out = (float*)d_out;

    // workspace: sumsS [1024*19] + sumsT [1024*19] floats = 155,648 B
    float* sumsS = (float*)d_ws;
    float* sumsT = sumsS + (size_t)2 * NUM_C * K;

    seg_sum_kernel<<<2 * NUM_C, NT, 0, stream>>>(S, T, lbl, sumsS, sumsT);
    finalize_kernel<<<1, NT, 0, stream>>>(sumsS, sumsT, lbl, out);
}

// Round 2
// 328.400 us; speedup vs baseline: 1.9544x; 1.9544x over previous
//
#include <hip/hip_runtime.h>

#define NUM_C 512
#define HW    32768     // 128*256
#define K     19
#define NT    256
#define CP    (NUM_C + 4)   // padded LDS row stride (516 floats) breaks 512-float bank alias

// ---------------------------------------------------------------------------
// K1: per-(b,c)-plane segment sums. grid = 1024 blocks x 256 threads.
// Hot loop is pure {3 vector loads + branchless fma into register
// accumulators} -- no LDS, no atomics, so waves pipeline freely.
// Per element: 19 x (v_cmp + v_cndmask + 2 v_fmac) = 76 VALU lane-ops.
// ---------------------------------------------------------------------------
__global__ __launch_bounds__(NT) void seg_sum_kernel(
    const float* __restrict__ S, const float* __restrict__ T,
    const int* __restrict__ lbl,
    float* __restrict__ sumsS, float* __restrict__ sumsT,
    float* __restrict__ out)
{
    const int tid   = threadIdx.x;
    const int plane = blockIdx.x;        // b*512 + c
    const int b     = plane >> 9;

    if (plane == 0 && tid == 0) out[0] = 0.f;   // zero-init for K2's atomicAdd

    const float4* S4 = (const float4*)(S + (size_t)plane * HW);
    const float4* T4 = (const float4*)(T + (size_t)plane * HW);
    const int4*   L4 = (const int4*)(lbl + (size_t)b * HW);

    float accS[K], accT[K];
#pragma unroll
    for (int k = 0; k < K; ++k) { accS[k] = 0.f; accT[k] = 0.f; }

    for (int i = tid; i < HW / 4; i += NT) {
        float4 s = S4[i];
        float4 t = T4[i];
        int4   l = L4[i];
#pragma unroll
        for (int k = 0; k < K; ++k) {
            float m;
            m = (l.x == k) ? 1.f : 0.f; accS[k] = fmaf(m, s.x, accS[k]); accT[k] = fmaf(m, t.x, accT[k]);
            m = (l.y == k) ? 1.f : 0.f; accS[k] = fmaf(m, s.y, accS[k]); accT[k] = fmaf(m, t.y, accT[k]);
            m = (l.z == k) ? 1.f : 0.f; accS[k] = fmaf(m, s.z, accS[k]); accT[k] = fmaf(m, t.z, accT[k]);
            m = (l.w == k) ? 1.f : 0.f; accS[k] = fmaf(m, s.w, accS[k]); accT[k] = fmaf(m, t.w, accT[k]);
        }
    }

    // cross-thread reduce: wave shuffle (6 steps) -> LDS (4 waves) -> global
    __shared__ float redS[4 * K], redT[4 * K];
    const int lane = tid & 63, wv = tid >> 6;
#pragma unroll
    for (int k = 0; k < K; ++k) {
        float vs = accS[k], vt = accT[k];
#pragma unroll
        for (int off = 32; off > 0; off >>= 1) {
            vs += __shfl_down(vs, off);
            vt += __shfl_down(vt, off);
        }
        if (lane == 0) { redS[wv * K + k] = vs; redT[wv * K + k] = vt; }
    }
    __syncthreads();
    if (tid < K) {
        sumsS[(size_t)plane * K + tid] = redS[tid] + redS[K + tid] + redS[2 * K + tid] + redS[3 * K + tid];
        sumsT[(size_t)plane * K + tid] = redT[tid] + redT[K + tid] + redT[2 * K + tid] + redT[3 * K + tid];
    }
}

// ---------------------------------------------------------------------------
// K2: grid = 2 blocks (one per batch). Register count-histogram, centers in
// padded LDS, float4 LDS dot products, atomicAdd partial loss into out.
// ---------------------------------------------------------------------------
__global__ __launch_bounds__(NT) void finalize_kernel(
    const float* __restrict__ sumsS, const float* __restrict__ sumsT,
    const int* __restrict__ lbl, float* __restrict__ out)
{
    __shared__ float centS[K * CP];
    __shared__ float centT[K * CP];
    __shared__ float cntf[K];
    __shared__ float dS[K * K], dT[K * K];
    __shared__ float red[NT];
    __shared__ int   redc[4 * K];
    const int tid = threadIdx.x;
    const int b   = blockIdx.x;

    // ---- exact label counts in registers (branchless) ----
    int cnt[K];
#pragma unroll
    for (int k = 0; k < K; ++k) cnt[k] = 0;
    const int4* L4 = (const int4*)(lbl + (size_t)b * HW);
    for (int i = tid; i < HW / 4; i += NT) {
        int4 l = L4[i];
#pragma unroll
        for (int k = 0; k < K; ++k)
            cnt[k] += (l.x == k) + (l.y == k) + (l.z == k) + (l.w == k);
    }
    const int lane = tid & 63, wv = tid >> 6;
#pragma unroll
    for (int k = 0; k < K; ++k) {
        int v = cnt[k];
#pragma unroll
        for (int off = 32; off > 0; off >>= 1) v += __shfl_down(v, off);
        if (lane == 0) redc[wv * K + k] = v;
    }
    __syncthreads();
    if (tid < K)
        cntf[tid] = (float)(redc[tid] + redc[K + tid] + redc[2 * K + tid] + redc[3 * K + tid]) + 1e-6f;
    __syncthreads();

    // ---- centers: [k][c] layout, padded stride ----
    for (int j = tid; j < NUM_C * K; j += NT) {
        int c = j / K, k = j - c * K;
        float cn = cntf[k];
        size_t gi = ((size_t)b * NUM_C + c) * K + k;
        centS[k * CP + c] = sumsS[gi] / cn;
        centT[k * CP + c] = sumsT[gi] / cn;
    }
    __syncthreads();

    // ---- pairwise dots: 2*361 tasks, float4 LDS reads ----
    for (int p = tid; p < 2 * K * K; p += NT) {
        int a  = p / (K * K);
        int ij = p - a * (K * K);
        int i  = ij / K, j = ij - (ij / K) * K;
        const float* base = a ? centT : centS;
        const float4* Ai = (const float4*)(base + i * CP);
        const float4* Aj = (const float4*)(base + j * CP);
        float d = 0.f;
        for (int c = 0; c < NUM_C / 4; ++c) {
            float4 x = Ai[c], y = Aj[c];
            d = fmaf(x.x, y.x, d); d = fmaf(x.y, y.y, d);
            d = fmaf(x.z, y.z, d); d = fmaf(x.w, y.w, d);
        }
        (a ? dT : dS)[ij] = d;
    }
    __syncthreads();

    // ---- cosine-normalize via diagonal + squared diff ----
    float acc = 0.f;
    for (int p = tid; p < K * K; p += NT) {
        int i = p / K, j = p - (p / K) * K;
        float nsi = fmaxf(sqrtf(dS[i * K + i]), 1e-8f);
        float nsj = fmaxf(sqrtf(dS[j * K + j]), 1e-8f);
        float nti = fmaxf(sqrtf(dT[i * K + i]), 1e-8f);
        float ntj = fmaxf(sqrtf(dT[j * K + j]), 1e-8f);
        float d = dS[p] / (nsi * nsj) - dT[p] / (nti * ntj);
        acc = fmaf(d, d, acc);
    }
    red[tid] = acc;
    __syncthreads();
    for (int s = NT / 2; s > 0; s >>= 1) {
        if (tid < s) red[tid] += red[tid + s];
        __syncthreads();
    }
    if (tid == 0)
        atomicAdd(out, red[0] * (1.0f / (2.0f * K * K)));  // mean over [B,K,K]
}

extern "C" void kernel_launch(void* const* d_in, const int* in_sizes, int n_in,
                              void* d_out, int out_size, void* d_ws, size_t ws_size,
                              hipStream_t stream) {
    const float* S   = (const float*)d_in[0];   // preds_S  [2,512,128,256] fp32
    const float* T   = (const float*)d_in[1];   // preds_T  [2,512,128,256] fp32
    const int*   lbl = (const int*)d_in[2];     // target   [2,1,128,256] int32
    float* out = (float*)d_out;

    float* sumsS = (float*)d_ws;                 // [1024*19]
    float* sumsT = sumsS + (size_t)2 * NUM_C * K;

    seg_sum_kernel<<<2 * NUM_C, NT, 0, stream>>>(S, T, lbl, sumsS, sumsT, out);
    finalize_kernel<<<2, NT, 0, stream>>>(sumsS, sumsT, lbl, out);
}